// Round 7
// baseline (158.907 us; speedup 1.0000x reference)
//
#include <hip/hip_runtime.h>
#include <hip/hip_bf16.h>
#include <stdint.h>

#define B_    4
#define N_    4096
#define FIN   64
#define NPROP 64
#define NFILT 128
#define KSEL  40
#define ROWS  (B_ * N_)
#define CAP   160
#define CAPP  176

typedef __attribute__((ext_vector_type(8))) short short8;
typedef __attribute__((ext_vector_type(4))) float f32x4;

__device__ __forceinline__ unsigned b16rne(float v) {
    unsigned u = __float_as_uint(v);
    return (u + 0x7FFFu + ((u >> 16) & 1u)) >> 16;
}
__device__ __forceinline__ float fromb16(unsigned h) {
    return __uint_as_float(h << 16);
}
// multiply both packed bf16 halves by -2 (sign flip + exponent+1); exact
__device__ __forceinline__ unsigned neg2pk(unsigned p) {
    return (p + 0x00800080u) ^ 0x80008000u;
}

// ---------------- K1: feat projection + bf16 hi/lo MFMA packs -------------
// Bpk[point] (2 x uint4 = 16 bf16):  k0..7 = [h(4), h(4)], k8..15 = [l(4), 1,1, nh, nl]
// A-fragment derived in k2:          k0..7 = [-2h, -2l],   k8..15 = [-2h, nh, nl, 1, 1]
// so  A.B = -2(h.h + l.h + h.l) + n_i + n_j = d^2 + O(1e-5)
__global__ __launch_bounds__(256) void k1_proj(
    const float* __restrict__ x, const float* __restrict__ Wf, const float* __restrict__ bf,
    const float* __restrict__ Ws, const float* __restrict__ bs,
    float* __restrict__ feat, uint4* __restrict__ Bpk)
{
    int wid  = threadIdx.x >> 6;
    int lane = threadIdx.x & 63;
    int row  = blockIdx.x * 4 + wid;

    float xv = x[row * FIN + lane];
    float acc = bf[lane];
    float c0 = bs[0], c1 = bs[1], c2 = bs[2], c3 = bs[3];
    #pragma unroll 16
    for (int k = 0; k < FIN; ++k) {
        float xk = __shfl(xv, k);
        acc += xk * Wf[k * NPROP + lane];
        float4 w4 = reinterpret_cast<const float4*>(Ws)[k];
        c0 += xk * w4.x; c1 += xk * w4.y; c2 += xk * w4.z; c3 += xk * w4.w;
    }
    feat[row * NPROP + lane] = acc;

    unsigned h0 = b16rne(c0), h1 = b16rne(c1), h2 = b16rne(c2), h3 = b16rne(c3);
    unsigned l0 = b16rne(c0 - fromb16(h0)), l1 = b16rne(c1 - fromb16(h1));
    unsigned l2 = b16rne(c2 - fromb16(h2)), l3 = b16rne(c3 - fromb16(h3));
    float n = c0 * c0; n = fmaf(c1, c1, n); n = fmaf(c2, c2, n); n = fmaf(c3, c3, n);
    unsigned nih = b16rne(n), nil = b16rne(n - fromb16(nih));
    unsigned v0 = h0 | (h1 << 16), v1 = h2 | (h3 << 16);
    unsigned v4 = l0 | (l1 << 16), v5 = l2 | (l3 << 16);
    unsigned on2 = 0x3F803F80u, nn = nih | (nil << 16);
    if (lane < 2) {
        uint4 p = lane ? make_uint4(v4, v5, on2, nn) : make_uint4(v0, v1, v0, v1);
        Bpk[row * 2 + lane] = p;
    }
}

// ---------------- K2: single-MFMA-pass exact top-40 -----------------------
// Block = 16-query strip, 8 waves x 512 candidates (32 MFMA tiles each).
// Pass 1: MFMA, pack d16 pairs in dreg[64] (compile-time indices only),
//         track per-(lane,row) minima on the d16 fields.
// tau:    merge 128->64 group minima, bitonic sort, take #39 (certified
//         upper bound on the true 40th-smallest d16 per row).
// Drain:  unrolled register scan, compact survivors (composite (d16<<12)|idx).
// Rank:   exact rank = #smaller survivors; ranks 1..39 = neighbor set.
// P4:     weights from d16 directly: w = exp(-10 * as_float(d16<<16)).
__global__ __launch_bounds__(512) void k2_knn(
    const uint4* __restrict__ Bpk, const float* __restrict__ feat,
    float* __restrict__ aggout)
{
    __shared__ unsigned minlds[16][129];
    __shared__ unsigned taulds[16];
    __shared__ unsigned survK[16][CAPP];
    __shared__ int      cnt[16];
    __shared__ unsigned winC[16][KSEL];

    int tid = threadIdx.x, w = tid >> 6, lane = tid & 63;
    int strip = blockIdx.x & 255;
    int b     = blockIdx.x >> 8;
    int q0    = strip * 16;
    int g = lane >> 4, li = lane & 15;
    size_t pbase = (size_t)b * N_;

    if (tid < 16) cnt[tid] = 0;

    // A fragment (block's 16 queries): zero for g>=2 (k16..31 unused)
    short8 afr;
    {
        union { uint4 u; short8 s; } cv;
        cv.u = make_uint4(0, 0, 0, 0);
        if (g < 2) {
            uint4 u0 = Bpk[(pbase + q0 + li) * 2 + 0];
            uint4 u1 = Bpk[(pbase + q0 + li) * 2 + 1];
            cv.u = (g == 0) ? make_uint4(neg2pk(u0.x), neg2pk(u0.y), neg2pk(u1.x), neg2pk(u1.y))
                            : make_uint4(neg2pk(u0.x), neg2pk(u0.y), u1.w, u1.z);
        }
        afr = cv.s;
    }

    bool selfC = (li >> 2) == g;          // lane holds a diagonal element (e = li&3)
    int  es    = li & 3;
    int  cbase = w * 512;
    int  tdiag = (w == (strip >> 5)) ? (strip & 31) : 64;   // uniform per wave

    // B loads unguarded: A zero in k16..31 makes g>=2 contributions 0.
    const uint4* bp = Bpk + (pbase + cbase + li) * 2 + (g & 1);

    // ---- pass 1: MFMA + d16 register store + min tracking ----
    unsigned dreg[64];
    unsigned m0 = ~0u, m1 = ~0u, m2 = ~0u, m3 = ~0u;   // rows g*4+{0..3}; 1,3 high-scaled
    uint4 pre0 = bp[0], pre1 = bp[32];
    #pragma unroll
    for (int t = 0; t < 32; ++t) {
        union { uint4 u; short8 s; } bv;
        bv.u = (t & 1) ? pre1 : pre0;
        if (t + 2 < 32) { if (t & 1) pre1 = bp[(t + 2) * 32]; else pre0 = bp[(t + 2) * 32]; }
        f32x4 d = __builtin_amdgcn_mfma_f32_16x16x32_bf16(afr, bv.s, (f32x4){0.f, 0.f, 0.f, 0.f}, 0, 0, 0);
        unsigned b0 = __float_as_uint(fmaxf(d[0], 0.0f));
        unsigned b1 = __float_as_uint(fmaxf(d[1], 0.0f));
        unsigned b2 = __float_as_uint(fmaxf(d[2], 0.0f));
        unsigned b3 = __float_as_uint(fmaxf(d[3], 0.0f));
        unsigned p0 = (b0 >> 16) | (b1 & 0xFFFF0000u);
        unsigned p1 = (b2 >> 16) | (b3 & 0xFFFF0000u);
        if (t == tdiag) {                 // force self -> d16 = 0
            if (selfC && es == 0) p0 &= 0xFFFF0000u;
            if (selfC && es == 1) p0 &= 0x0000FFFFu;
            if (selfC && es == 2) p1 &= 0xFFFF0000u;
            if (selfC && es == 3) p1 &= 0x0000FFFFu;
        }
        dreg[2 * t]     = p0;
        dreg[2 * t + 1] = p1;
        m0 = min(m0, p0 & 0x0000FFFFu);
        m1 = min(m1, p0 & 0xFFFF0000u);
        m2 = min(m2, p1 & 0x0000FFFFu);
        m3 = min(m3, p1 & 0xFFFF0000u);
    }
    minlds[g * 4 + 0][w * 16 + li] = m0;
    minlds[g * 4 + 1][w * 16 + li] = m1;
    minlds[g * 4 + 2][w * 16 + li] = m2;
    minlds[g * 4 + 3][w * 16 + li] = m3;
    __syncthreads();

    // ---- tau: merge 128 -> 64 group minima, bitonic sort, take #39 ----
    unsigned sv[2];
    #pragma unroll
    for (int e = 0; e < 2; ++e) {
        int r = 2 * w + e;
        sv[e] = min(minlds[r][lane], minlds[r][64 + lane]);
    }
    #pragma unroll
    for (int k = 2; k <= 64; k <<= 1) {
        #pragma unroll
        for (int j2 = k >> 1; j2 >= 1; j2 >>= 1) {
            bool up = (((lane & k) == 0) == ((lane & j2) == 0));
            #pragma unroll
            for (int e = 0; e < 2; ++e) {
                unsigned o = (unsigned)__shfl_xor((int)sv[e], j2);
                sv[e] = up ? min(sv[e], o) : max(sv[e], o);
            }
        }
    }
    if (lane == 39) { taulds[2 * w] = sv[0]; taulds[2 * w + 1] = sv[1]; }
    __syncthreads();

    unsigned tau0 = taulds[g * 4 + 0], tau1 = taulds[g * 4 + 1];
    unsigned tau2 = taulds[g * 4 + 2], tau3 = taulds[g * 4 + 3];

    // ---- drain: register scan, compact survivors ----
    #pragma unroll
    for (int t = 0; t < 32; ++t) {
        unsigned p0 = dreg[2 * t], p1 = dreg[2 * t + 1];
        unsigned idx = (unsigned)(cbase + t * 16 + li);
        if ((p0 & 0x0000FFFFu) <= tau0) {
            unsigned c = ((p0 & 0xFFFFu) << 12) | idx;
            int s = atomicAdd(&cnt[g * 4 + 0], 1); if (s < CAP) survK[g * 4 + 0][s] = c;
        }
        if ((p0 & 0xFFFF0000u) <= tau1) {
            unsigned c = ((p0 >> 4) & 0xFFFF000u) | idx;
            int s = atomicAdd(&cnt[g * 4 + 1], 1); if (s < CAP) survK[g * 4 + 1][s] = c;
        }
        if ((p1 & 0x0000FFFFu) <= tau2) {
            unsigned c = ((p1 & 0xFFFFu) << 12) | idx;
            int s = atomicAdd(&cnt[g * 4 + 2], 1); if (s < CAP) survK[g * 4 + 2][s] = c;
        }
        if ((p1 & 0xFFFF0000u) <= tau3) {
            unsigned c = ((p1 >> 4) & 0xFFFF000u) | idx;
            int s = atomicAdd(&cnt[g * 4 + 3], 1); if (s < CAP) survK[g * 4 + 3][s] = c;
        }
    }
    __syncthreads();

    // ---- rank survivors; ranks 1..39 -> winners (2 rows per wave) ----
    #pragma unroll
    for (int e = 0; e < 2; ++e) {
        int r = 2 * w + e;
        int S = min(cnt[r], CAP);
        if (lane < 16) survK[r][S + lane] = 0xFFFFFFFFu;      // sentinels
        for (int rr = lane; rr < S; rr += 64) {
            unsigned my = survK[r][rr];
            int c = 0;
            int S4 = (S + 3) >> 2;
            for (int s4 = 0; s4 < S4; ++s4) {
                uint4 u4 = *reinterpret_cast<const uint4*>(&survK[r][4 * s4]);
                c += (u4.x < my) + (u4.y < my) + (u4.z < my) + (u4.w < my);
            }
            if (c >= 1 && c < KSEL) winC[r][c - 1] = my;
        }
    }

    // ---- P4: aggregate 39 winners; weight from stored d16 ----
    const float* fb = feat + pbase * NPROP + lane;
    #pragma unroll 1
    for (int e = 0; e < 2; ++e) {
        int r = 2 * w + e;
        int qi = q0 + r;
        float mx = -3.4e38f, sm = 0.f;
        #pragma unroll 4
        for (int u = 0; u < KSEL / 4; ++u) {
            uint4 cv4 = *reinterpret_cast<const uint4*>(&winC[r][4 * u]);
            #pragma unroll
            for (int e2 = 0; e2 < 4; ++e2) {
                if (4 * u + e2 > KSEL - 2) break;             // compile-time tail skip
                unsigned comp = (e2 == 0) ? cv4.x : (e2 == 1) ? cv4.y : (e2 == 2) ? cv4.z : cv4.w;
                int j = (int)(comp & 0xFFFu);
                float dd = __uint_as_float((comp >> 12) << 16);
                float wt = __expf(-10.f * dd);
                float f  = fb[(size_t)j * NPROP];
                float wf = wt * f;
                mx = fmaxf(mx, wf);
                sm += wf;
            }
        }
        aggout[(size_t)(pbase + qi) * NFILT + lane]      = mx;
        aggout[(size_t)(pbase + qi) * NFILT + 64 + lane] = sm * (1.0f / 39.0f);
    }
}

// ---------------- K3: out = [x | max | mean] @ W_out + b_out --------------
__global__ __launch_bounds__(512) void k3_out(
    const float* __restrict__ x, const float* __restrict__ agg,
    const float* __restrict__ Wo, const float* __restrict__ bo,
    float* __restrict__ out)
{
    __shared__ float xa[32 * FIN];    // 8 KB
    __shared__ float ga[32 * NFILT];  // 16 KB
    int tid = threadIdx.x;
    int r0  = blockIdx.x * 32;
    for (int idx = tid; idx < 32 * FIN / 4; idx += 512)
        reinterpret_cast<float4*>(xa)[idx] =
            reinterpret_cast<const float4*>(x + (size_t)r0 * FIN)[idx];
    for (int idx = tid; idx < 32 * NFILT / 4; idx += 512)
        reinterpret_cast<float4*>(ga)[idx] =
            reinterpret_cast<const float4*>(agg + (size_t)r0 * NFILT)[idx];
    __syncthreads();

    int c = tid & 127, rg = tid >> 7;
    float acc[8];
    float bb = bo[c];
    #pragma unroll
    for (int r = 0; r < 8; ++r) acc[r] = bb;

    #pragma unroll 4
    for (int k = 0; k < FIN; k += 4) {
        float w0 = Wo[(k + 0) * NFILT + c];
        float w1 = Wo[(k + 1) * NFILT + c];
        float w2 = Wo[(k + 2) * NFILT + c];
        float w3 = Wo[(k + 3) * NFILT + c];
        #pragma unroll
        for (int r = 0; r < 8; ++r) {
            float4 xv = *reinterpret_cast<const float4*>(&xa[(rg * 8 + r) * FIN + k]);
            acc[r] = fmaf(xv.x, w0, fmaf(xv.y, w1, fmaf(xv.z, w2, fmaf(xv.w, w3, acc[r]))));
        }
    }
    #pragma unroll 4
    for (int k = 0; k < NFILT; k += 4) {
        float w0 = Wo[(FIN + k + 0) * NFILT + c];
        float w1 = Wo[(FIN + k + 1) * NFILT + c];
        float w2 = Wo[(FIN + k + 2) * NFILT + c];
        float w3 = Wo[(FIN + k + 3) * NFILT + c];
        #pragma unroll
        for (int r = 0; r < 8; ++r) {
            float4 gv = *reinterpret_cast<const float4*>(&ga[(rg * 8 + r) * NFILT + k]);
            acc[r] = fmaf(gv.x, w0, fmaf(gv.y, w1, fmaf(gv.z, w2, fmaf(gv.w, w3, acc[r]))));
        }
    }
    #pragma unroll
    for (int r = 0; r < 8; ++r)
        out[(size_t)(r0 + rg * 8 + r) * NFILT + c] = acc[r];
}

extern "C" void kernel_launch(void* const* d_in, const int* in_sizes, int n_in,
                              void* d_out, int out_size, void* d_ws, size_t ws_size,
                              hipStream_t stream)
{
    const float* x  = (const float*)d_in[0];
    const float* Wf = (const float*)d_in[1];
    const float* bf = (const float*)d_in[2];
    const float* Ws = (const float*)d_in[3];
    const float* bs = (const float*)d_in[4];
    const float* Wo = (const float*)d_in[5];
    const float* bo = (const float*)d_in[6];
    float* out = (float*)d_out;

    float* feat = (float*)d_ws;                                       // 4 MB
    uint4* Bpk  = (uint4*)((char*)d_ws + (size_t)ROWS * NPROP * 4);   // 512 KB

    k1_proj<<<ROWS / 4, 256, 0, stream>>>(x, Wf, bf, Ws, bs, feat, Bpk);
    k2_knn <<<B_ * 256, 512, 0, stream>>>(Bpk, feat, out);
    k3_out <<<ROWS / 32, 512, 0, stream>>>(x, out, Wo, bo, out);
}

// Round 8
// 100.096 us; speedup vs baseline: 1.5875x; 1.5875x over previous
//
#include <hip/hip_runtime.h>
#include <hip/hip_bf16.h>
#include <stdint.h>

#define B_    4
#define N_    4096
#define FIN   64
#define NPROP 64
#define NFILT 128
#define KSEL  40
#define ROWS  (B_ * N_)
#define CAP   160
#define CAPP  176

typedef __attribute__((ext_vector_type(8))) short short8;
typedef __attribute__((ext_vector_type(4))) float f32x4;

__device__ __forceinline__ unsigned b16rne(float v) {
    unsigned u = __float_as_uint(v);
    return (u + 0x7FFFu + ((u >> 16) & 1u)) >> 16;
}
__device__ __forceinline__ float fromb16(unsigned h) {
    return __uint_as_float(h << 16);
}
// multiply both packed bf16 halves by -2 (sign flip + exponent+1); exact
__device__ __forceinline__ unsigned neg2pk(unsigned p) {
    return (p + 0x00800080u) ^ 0x80008000u;
}

// ---------------- K0: pack W_out into bf16 hi/lo MFMA-B layout ------------
// Wpk[c][k'] (ushort, k' = 0..575): seg0 k'=k      : wh(W[k][c])
//                                   seg1 k'=192+k  : wh(W[k][c])
//                                   seg2 k'=384+k  : wl(W[k][c])
// pairs with A = (uh, ul, uh):  sum = uh*wh + ul*wh + uh*wl ~= u*w
__global__ __launch_bounds__(192) void k0_packW(
    const float* __restrict__ Wo, unsigned short* __restrict__ Wpk)
{
    int c = blockIdx.x, k = threadIdx.x;
    float wv = Wo[k * NFILT + c];
    unsigned wh = b16rne(wv);
    unsigned wl = b16rne(wv - fromb16(wh));
    Wpk[(size_t)c * 576 + k]       = (unsigned short)wh;
    Wpk[(size_t)c * 576 + 192 + k] = (unsigned short)wh;
    Wpk[(size_t)c * 576 + 384 + k] = (unsigned short)wl;
}

// ---------------- K1: feat projection + bf16 hi/lo MFMA packs -------------
// Bpk[point] (2 x uint4 = 16 bf16):  k0..7 = [h(4), h(4)], k8..15 = [l(4), 1,1, nh, nl]
// A-fragment derived in k2:          k0..7 = [-2h, -2l],   k8..15 = [-2h, nh, nl, 1, 1]
// so  A.B = -2(h.h + l.h + h.l) + n_i + n_j = d^2 + O(1e-5)
__global__ __launch_bounds__(256) void k1_proj(
    const float* __restrict__ x, const float* __restrict__ Wf, const float* __restrict__ bf,
    const float* __restrict__ Ws, const float* __restrict__ bs,
    float* __restrict__ feat, uint4* __restrict__ Bpk)
{
    int wid  = threadIdx.x >> 6;
    int lane = threadIdx.x & 63;
    int row  = blockIdx.x * 4 + wid;

    float xv = x[row * FIN + lane];
    float acc = bf[lane];
    float c0 = bs[0], c1 = bs[1], c2 = bs[2], c3 = bs[3];
    #pragma unroll 16
    for (int k = 0; k < FIN; ++k) {
        float xk = __shfl(xv, k);
        acc += xk * Wf[k * NPROP + lane];
        float4 w4 = reinterpret_cast<const float4*>(Ws)[k];
        c0 += xk * w4.x; c1 += xk * w4.y; c2 += xk * w4.z; c3 += xk * w4.w;
    }
    feat[row * NPROP + lane] = acc;

    unsigned h0 = b16rne(c0), h1 = b16rne(c1), h2 = b16rne(c2), h3 = b16rne(c3);
    unsigned l0 = b16rne(c0 - fromb16(h0)), l1 = b16rne(c1 - fromb16(h1));
    unsigned l2 = b16rne(c2 - fromb16(h2)), l3 = b16rne(c3 - fromb16(h3));
    float n = c0 * c0; n = fmaf(c1, c1, n); n = fmaf(c2, c2, n); n = fmaf(c3, c3, n);
    unsigned nih = b16rne(n), nil = b16rne(n - fromb16(nih));
    unsigned v0 = h0 | (h1 << 16), v1 = h2 | (h3 << 16);
    unsigned v4 = l0 | (l1 << 16), v5 = l2 | (l3 << 16);
    unsigned on2 = 0x3F803F80u, nn = nih | (nil << 16);
    if (lane < 2) {
        uint4 p = lane ? make_uint4(v4, v5, on2, nn) : make_uint4(v0, v1, v0, v1);
        Bpk[row * 2 + lane] = p;
    }
}

// ---------------- K2: MFMA KNN top-40 + fused output GEMM epilogue --------
// Block = 16-query strip, 8 waves x 512 candidates (32 MFMA tiles each).
// Core = R6 two-pass certified-threshold (validated 71.5us), then P4 keeps
// agg in registers, packs U=[x|max|mean] hi/lo into LDS, and 8 waves run the
// 18-step MFMA output GEMM (one 16x16 out tile each) -> d_out. k3 deleted.
__global__ __launch_bounds__(512) void k2_knn(
    const uint4* __restrict__ Bpk, const float* __restrict__ feat,
    const float* __restrict__ x, const unsigned short* __restrict__ Wpk,
    const float* __restrict__ bo, float* __restrict__ out)
{
    __shared__ unsigned minlds[16][129];
    __shared__ unsigned taulds[16];
    __shared__ unsigned survK[16][CAPP];
    __shared__ int      cnt[16];
    __shared__ unsigned winC[16][KSEL];
    __shared__ unsigned short Upk[16][392];   // U hi at f, lo at 192+f; pad->392

    int tid = threadIdx.x, w = tid >> 6, lane = tid & 63;
    int strip = blockIdx.x & 255;
    int b     = blockIdx.x >> 8;
    int q0    = strip * 16;
    int g = lane >> 4, li = lane & 15;
    size_t pbase = (size_t)b * N_;

    if (tid < 16) cnt[tid] = 0;

    // A fragment (block's 16 queries), derived from Bpk
    short8 afr;
    {
        union { uint4 u; short8 s; } cv;
        cv.u = make_uint4(0, 0, 0, 0);
        if (g < 2) {
            uint4 u0 = Bpk[(pbase + q0 + li) * 2 + 0];
            uint4 u1 = Bpk[(pbase + q0 + li) * 2 + 1];
            cv.u = (g == 0) ? make_uint4(neg2pk(u0.x), neg2pk(u0.y), neg2pk(u1.x), neg2pk(u1.y))
                            : make_uint4(neg2pk(u0.x), neg2pk(u0.y), u1.w, u1.z);
        }
        afr = cv.s;
    }

    bool selfC = (li >> 2) == g;          // lane holds a diagonal element (e = li&3)
    int  es    = li & 3;
    int  cbase = w * 512;

    // ---- pass 1: group-min keys (no storage), prefetched B loads ----
    unsigned m0 = ~0u, m1 = ~0u, m2 = ~0u, m3 = ~0u;
    uint4 nb = make_uint4(0, 0, 0, 0);
    if (g < 2) nb = Bpk[(pbase + cbase + li) * 2 + g];
    #pragma unroll 4
    for (int t = 0; t < 32; ++t) {
        union { uint4 u; short8 s; } bv; bv.u = nb;
        if (t < 31 && g < 2) nb = Bpk[(pbase + cbase + (t + 1) * 16 + li) * 2 + g];
        f32x4 d = __builtin_amdgcn_mfma_f32_16x16x32_bf16(afr, bv.s, (f32x4){0.f, 0.f, 0.f, 0.f}, 0, 0, 0);
        unsigned idx = (unsigned)((cbase + t * 16) | li);
        m0 = min(m0, (__float_as_uint(fmaxf(d[0], 1e-30f)) & 0xFFFFF000u) | idx);
        m1 = min(m1, (__float_as_uint(fmaxf(d[1], 1e-30f)) & 0xFFFFF000u) | idx);
        m2 = min(m2, (__float_as_uint(fmaxf(d[2], 1e-30f)) & 0xFFFFF000u) | idx);
        m3 = min(m3, (__float_as_uint(fmaxf(d[3], 1e-30f)) & 0xFFFFF000u) | idx);
    }
    minlds[g * 4 + 0][w * 16 + li] = m0;
    minlds[g * 4 + 1][w * 16 + li] = m1;
    minlds[g * 4 + 2][w * 16 + li] = m2;
    minlds[g * 4 + 3][w * 16 + li] = m3;
    __syncthreads();

    // ---- tau: merge 128 -> 64 group minima, bitonic sort, take #39 ----
    unsigned sv[2];
    #pragma unroll
    for (int e = 0; e < 2; ++e) {
        int r = 2 * w + e;
        sv[e] = min(minlds[r][lane], minlds[r][64 + lane]);
    }
    #pragma unroll
    for (int k = 2; k <= 64; k <<= 1) {
        #pragma unroll
        for (int j2 = k >> 1; j2 >= 1; j2 >>= 1) {
            bool up = (((lane & k) == 0) == ((lane & j2) == 0));
            #pragma unroll
            for (int e = 0; e < 2; ++e) {
                unsigned o = (unsigned)__shfl_xor((int)sv[e], j2);
                sv[e] = up ? min(sv[e], o) : max(sv[e], o);
            }
        }
    }
    if (lane == 39) { taulds[2 * w] = sv[0]; taulds[2 * w + 1] = sv[1]; }
    __syncthreads();

    unsigned tau0 = taulds[g * 4 + 0], tau1 = taulds[g * 4 + 1];
    unsigned tau2 = taulds[g * 4 + 2], tau3 = taulds[g * 4 + 3];
    int tdiag = (w == (strip >> 5)) ? (strip & 31) : 64;      // uniform per wave

    // ---- pass 2: re-stream via MFMA, compact survivors ----
    nb = make_uint4(0, 0, 0, 0);
    if (g < 2) nb = Bpk[(pbase + cbase + li) * 2 + g];
    #pragma unroll 2
    for (int t = 0; t < 32; ++t) {
        union { uint4 u; short8 s; } bv; bv.u = nb;
        if (t < 31 && g < 2) nb = Bpk[(pbase + cbase + (t + 1) * 16 + li) * 2 + g];
        f32x4 d = __builtin_amdgcn_mfma_f32_16x16x32_bf16(afr, bv.s, (f32x4){0.f, 0.f, 0.f, 0.f}, 0, 0, 0);
        unsigned idx = (unsigned)((cbase + t * 16) | li);
        unsigned k0 = (__float_as_uint(fmaxf(d[0], 1e-30f)) & 0xFFFFF000u) | idx;
        unsigned k1 = (__float_as_uint(fmaxf(d[1], 1e-30f)) & 0xFFFFF000u) | idx;
        unsigned k2 = (__float_as_uint(fmaxf(d[2], 1e-30f)) & 0xFFFFF000u) | idx;
        unsigned k3 = (__float_as_uint(fmaxf(d[3], 1e-30f)) & 0xFFFFF000u) | idx;
        if (t == tdiag) {                                     // force self -> rank 0
            if (selfC && es == 0) k0 = 0u;
            if (selfC && es == 1) k1 = 0u;
            if (selfC && es == 2) k2 = 0u;
            if (selfC && es == 3) k3 = 0u;
        }
        if (k0 <= tau0) { int s = atomicAdd(&cnt[g * 4 + 0], 1); if (s < CAP) survK[g * 4 + 0][s] = k0; }
        if (k1 <= tau1) { int s = atomicAdd(&cnt[g * 4 + 1], 1); if (s < CAP) survK[g * 4 + 1][s] = k1; }
        if (k2 <= tau2) { int s = atomicAdd(&cnt[g * 4 + 2], 1); if (s < CAP) survK[g * 4 + 2][s] = k2; }
        if (k3 <= tau3) { int s = atomicAdd(&cnt[g * 4 + 3], 1); if (s < CAP) survK[g * 4 + 3][s] = k3; }
    }
    __syncthreads();

    // ---- rank survivors; ranks 1..39 -> winners (2 rows per wave) ----
    #pragma unroll
    for (int e = 0; e < 2; ++e) {
        int r = 2 * w + e;
        int S = min(cnt[r], CAP);
        if (lane < 16) survK[r][S + lane] = 0xFFFFFFFFu;      // sentinels
        for (int rr = lane; rr < S; rr += 64) {
            unsigned my = survK[r][rr];
            int c = 0;
            int S4 = (S + 3) >> 2;
            for (int s4 = 0; s4 < S4; ++s4) {
                uint4 u4 = *reinterpret_cast<const uint4*>(&survK[r][4 * s4]);
                c += (u4.x < my) + (u4.y < my) + (u4.z < my) + (u4.w < my);
            }
            if (c >= 1 && c < KSEL) winC[r][c - 1] = my;
        }
    }
    __syncthreads();

    // ---- P4: aggregate 39 winners; weight from key's 20-bit dist field;
    //          pack U = [x | max | mean] hi/lo into Upk ----
    const float* fb = feat + pbase * NPROP + lane;
    #pragma unroll 1
    for (int e = 0; e < 2; ++e) {
        int r = 2 * w + e;
        int qi = q0 + r;
        float mx = -3.4e38f, sm = 0.f;
        #pragma unroll 4
        for (int u = 0; u < KSEL / 4; ++u) {
            uint4 cv4 = *reinterpret_cast<const uint4*>(&winC[r][4 * u]);
            #pragma unroll
            for (int e2 = 0; e2 < 4; ++e2) {
                if (4 * u + e2 > KSEL - 2) break;             // compile-time tail skip
                unsigned comp = (e2 == 0) ? cv4.x : (e2 == 1) ? cv4.y : (e2 == 2) ? cv4.z : cv4.w;
                int j = (int)(comp & 0xFFFu);
                float dd = __uint_as_float(comp & 0xFFFFF000u);
                float wt = __expf(-10.f * dd);
                float f  = fb[(size_t)j * NPROP];
                float wf = wt * f;
                mx = fmaxf(mx, wf);
                sm += wf;
            }
        }
        float mean = sm * (1.0f / 39.0f);
        unsigned mh = b16rne(mx),   ml = b16rne(mx - fromb16(mh));
        unsigned eh = b16rne(mean), el = b16rne(mean - fromb16(eh));
        float xv = x[(pbase + qi) * FIN + lane];
        unsigned xh = b16rne(xv),   xl = b16rne(xv - fromb16(xh));
        Upk[r][lane]       = (unsigned short)xh;
        Upk[r][192 + lane] = (unsigned short)xl;
        Upk[r][64 + lane]  = (unsigned short)mh;
        Upk[r][256 + lane] = (unsigned short)ml;
        Upk[r][128 + lane] = (unsigned short)eh;
        Upk[r][320 + lane] = (unsigned short)el;
    }
    __syncthreads();

    // ---- epilogue: out[16 x 128] = U @ W_out + b_out via MFMA ----
    // wave w computes cols [16w, 16w+16); A = (uh, ul, uh), B = (wh, wh, wl)
    {
        int colc = w * 16 + li;
        const unsigned short* wp = Wpk + (size_t)colc * 576;
        f32x4 oacc = {0.f, 0.f, 0.f, 0.f};
        #pragma unroll
        for (int s = 0; s < 18; ++s) {
            int koff = (s < 6)  ? (32 * s + 8 * g)
                     : (s < 12) ? (192 + 32 * (s - 6) + 8 * g)
                                : (32 * (s - 12) + 8 * g);
            union { uint4 u; short8 s8; } av, bv;
            av.u = *reinterpret_cast<const uint4*>(&Upk[li][koff]);
            bv.u = *reinterpret_cast<const uint4*>(&wp[32 * s + 8 * g]);
            oacc = __builtin_amdgcn_mfma_f32_16x16x32_bf16(av.s8, bv.s8, oacc, 0, 0, 0);
        }
        float bb = bo[colc];
        #pragma unroll
        for (int e = 0; e < 4; ++e) {
            int orow = g * 4 + e;
            out[(size_t)(pbase + q0 + orow) * NFILT + colc] = oacc[e] + bb;
        }
    }
}

extern "C" void kernel_launch(void* const* d_in, const int* in_sizes, int n_in,
                              void* d_out, int out_size, void* d_ws, size_t ws_size,
                              hipStream_t stream)
{
    const float* x  = (const float*)d_in[0];
    const float* Wf = (const float*)d_in[1];
    const float* bf = (const float*)d_in[2];
    const float* Ws = (const float*)d_in[3];
    const float* bs = (const float*)d_in[4];
    const float* Wo = (const float*)d_in[5];
    const float* bo = (const float*)d_in[6];
    float* out = (float*)d_out;

    float*          feat = (float*)d_ws;                                       // 4 MB
    uint4*          Bpk  = (uint4*)((char*)d_ws + (size_t)ROWS * NPROP * 4);   // 512 KB
    unsigned short* Wpk  = (unsigned short*)((char*)d_ws
                             + (size_t)ROWS * NPROP * 4 + (size_t)ROWS * 32);  // 144 KB

    k0_packW<<<NFILT, 192, 0, stream>>>(Wo, Wpk);
    k1_proj <<<ROWS / 4, 256, 0, stream>>>(x, Wf, bf, Ws, bs, feat, Bpk);
    k2_knn  <<<B_ * 256, 512, 0, stream>>>(Bpk, feat, x, Wpk, bo, out);
}

// Round 9
// 92.302 us; speedup vs baseline: 1.7216x; 1.0844x over previous
//
#include <hip/hip_runtime.h>
#include <hip/hip_bf16.h>
#include <stdint.h>

#define B_    4
#define N_    4096
#define FIN   64
#define NPROP 64
#define NFILT 128
#define KSEL  40
#define ROWS  (B_ * N_)
#define CAP   160
#define CAPP  176

typedef __attribute__((ext_vector_type(8))) short short8;
typedef __attribute__((ext_vector_type(4))) float f32x4;

__device__ __forceinline__ unsigned b16rne(float v) {
    unsigned u = __float_as_uint(v);
    return (u + 0x7FFFu + ((u >> 16) & 1u)) >> 16;
}
__device__ __forceinline__ float fromb16(unsigned h) {
    return __uint_as_float(h << 16);
}
// multiply both packed bf16 halves by -2 (sign flip + exponent+1); exact
__device__ __forceinline__ unsigned neg2pk(unsigned p) {
    return (p + 0x00800080u) ^ 0x80008000u;
}

// ---------------- K0: pack W_out into bf16 hi/lo MFMA-B layout ------------
__global__ __launch_bounds__(192) void k0_packW(
    const float* __restrict__ Wo, unsigned short* __restrict__ Wpk)
{
    int c = blockIdx.x, k = threadIdx.x;
    float wv = Wo[k * NFILT + c];
    unsigned wh = b16rne(wv);
    unsigned wl = b16rne(wv - fromb16(wh));
    Wpk[(size_t)c * 576 + k]       = (unsigned short)wh;
    Wpk[(size_t)c * 576 + 192 + k] = (unsigned short)wh;
    Wpk[(size_t)c * 576 + 384 + k] = (unsigned short)wl;
}

// ---------------- K1: feat projection + bf16 hi/lo MFMA packs -------------
// Bpk[point] (2 x uint4 = 16 bf16):  k0..7 = [h(4), h(4)], k8..15 = [l(4), 1,1, nh, nl]
// A-fragment derived in k2:          k0..7 = [-2h, -2l],   k8..15 = [-2h, nh, nl, 1, 1]
// so  A.B = -2(h.h + l.h + h.l) + n_i + n_j = d^2 + O(1e-5)
__global__ __launch_bounds__(256) void k1_proj(
    const float* __restrict__ x, const float* __restrict__ Wf, const float* __restrict__ bf,
    const float* __restrict__ Ws, const float* __restrict__ bs,
    float* __restrict__ feat, uint4* __restrict__ Bpk)
{
    int wid  = threadIdx.x >> 6;
    int lane = threadIdx.x & 63;
    int row  = blockIdx.x * 4 + wid;

    float xv = x[row * FIN + lane];
    float acc = bf[lane];
    float c0 = bs[0], c1 = bs[1], c2 = bs[2], c3 = bs[3];
    #pragma unroll 16
    for (int k = 0; k < FIN; ++k) {
        float xk = __shfl(xv, k);
        acc += xk * Wf[k * NPROP + lane];
        float4 w4 = reinterpret_cast<const float4*>(Ws)[k];
        c0 += xk * w4.x; c1 += xk * w4.y; c2 += xk * w4.z; c3 += xk * w4.w;
    }
    feat[row * NPROP + lane] = acc;

    unsigned h0 = b16rne(c0), h1 = b16rne(c1), h2 = b16rne(c2), h3 = b16rne(c3);
    unsigned l0 = b16rne(c0 - fromb16(h0)), l1 = b16rne(c1 - fromb16(h1));
    unsigned l2 = b16rne(c2 - fromb16(h2)), l3 = b16rne(c3 - fromb16(h3));
    float n = c0 * c0; n = fmaf(c1, c1, n); n = fmaf(c2, c2, n); n = fmaf(c3, c3, n);
    unsigned nih = b16rne(n), nil = b16rne(n - fromb16(nih));
    unsigned v0 = h0 | (h1 << 16), v1 = h2 | (h3 << 16);
    unsigned v4 = l0 | (l1 << 16), v5 = l2 | (l3 << 16);
    unsigned on2 = 0x3F803F80u, nn = nih | (nil << 16);
    if (lane < 2) {
        uint4 p = lane ? make_uint4(v4, v5, on2, nn) : make_uint4(v0, v1, v0, v1);
        Bpk[row * 2 + lane] = p;
    }
}

// ---------------- K2: MFMA KNN top-40 + fused output GEMM epilogue --------
// Block = 16-query strip, 8 waves x 512 candidates (32 MFMA tiles each).
// Pass 1: MFMA + plain float-min per row (1 VALU/value) -> block minima.
// tau:    clamp+mask block minima, bitonic sort, tau = v39 | 0xFFF.
//   Certificate: each block's min (keyed with the max idx suffix) upper-
//   bounds that block's best candidate key, so the 40 smallest block-mins
//   certify 40 distinct candidate keys <= tau >= true-40th key.
// Pass 2: survivor test = single float cmp d <= tauF (provably identical
//   accept-set to unsigned key<=tau); key built only in rare accept body.
// Rank:   exact rank = #smaller survivors; ranks 1..39 = neighbor set.
// P4:     weights from key's 20-bit dist field; epilogue GEMM via MFMA.
__global__ __launch_bounds__(512) void k2_knn(
    const uint4* __restrict__ Bpk, const float* __restrict__ feat,
    const float* __restrict__ x, const unsigned short* __restrict__ Wpk,
    const float* __restrict__ bo, float* __restrict__ out)
{
    __shared__ unsigned minlds[16][129];
    __shared__ unsigned taulds[16];
    __shared__ unsigned survK[16][CAPP];
    __shared__ int      cnt[16];
    __shared__ unsigned winC[16][KSEL];
    __shared__ unsigned short Upk[16][392];   // U hi at f, lo at 192+f

    int tid = threadIdx.x, w = tid >> 6, lane = tid & 63;
    int strip = blockIdx.x & 255;
    int b     = blockIdx.x >> 8;
    int q0    = strip * 16;
    int g = lane >> 4, li = lane & 15;
    size_t pbase = (size_t)b * N_;

    if (tid < 16) cnt[tid] = 0;

    // A fragment (block's 16 queries), derived from Bpk
    short8 afr;
    {
        union { uint4 u; short8 s; } cv;
        cv.u = make_uint4(0, 0, 0, 0);
        if (g < 2) {
            uint4 u0 = Bpk[(pbase + q0 + li) * 2 + 0];
            uint4 u1 = Bpk[(pbase + q0 + li) * 2 + 1];
            cv.u = (g == 0) ? make_uint4(neg2pk(u0.x), neg2pk(u0.y), neg2pk(u1.x), neg2pk(u1.y))
                            : make_uint4(neg2pk(u0.x), neg2pk(u0.y), u1.w, u1.z);
        }
        afr = cv.s;
    }

    bool selfC = (li >> 2) == g;          // lane holds a diagonal element (e = li&3)
    int  es    = li & 3;
    int  cbase = w * 512;

    // B loads unguarded: A zero in k16..31 makes g>=2 contributions 0.
    const uint4* bp = Bpk + (pbase + cbase + li) * 2 + (g & 1);

    // ---- pass 1: MFMA + plain float min per row ----
    float f0 = 1e30f, f1 = 1e30f, f2 = 1e30f, f3 = 1e30f;
    uint4 nb = bp[0];
    #pragma unroll 4
    for (int t = 0; t < 32; ++t) {
        union { uint4 u; short8 s; } bv; bv.u = nb;
        if (t < 31) nb = bp[(t + 1) * 32];
        f32x4 d = __builtin_amdgcn_mfma_f32_16x16x32_bf16(afr, bv.s, (f32x4){0.f, 0.f, 0.f, 0.f}, 0, 0, 0);
        f0 = fminf(f0, d[0]);
        f1 = fminf(f1, d[1]);
        f2 = fminf(f2, d[2]);
        f3 = fminf(f3, d[3]);
    }
    minlds[g * 4 + 0][w * 16 + li] = __float_as_uint(fmaxf(f0, 0.0f));
    minlds[g * 4 + 1][w * 16 + li] = __float_as_uint(fmaxf(f1, 0.0f));
    minlds[g * 4 + 2][w * 16 + li] = __float_as_uint(fmaxf(f2, 0.0f));
    minlds[g * 4 + 3][w * 16 + li] = __float_as_uint(fmaxf(f3, 0.0f));
    __syncthreads();

    // ---- tau: merge 128 -> 64 group minima, bitonic sort, take #39 ----
    unsigned sv[2];
    #pragma unroll
    for (int e = 0; e < 2; ++e) {
        int r = 2 * w + e;
        sv[e] = min(minlds[r][lane], minlds[r][64 + lane]);
    }
    #pragma unroll
    for (int k = 2; k <= 64; k <<= 1) {
        #pragma unroll
        for (int j2 = k >> 1; j2 >= 1; j2 >>= 1) {
            bool up = (((lane & k) == 0) == ((lane & j2) == 0));
            #pragma unroll
            for (int e = 0; e < 2; ++e) {
                unsigned o = (unsigned)__shfl_xor((int)sv[e], j2);
                sv[e] = up ? min(sv[e], o) : max(sv[e], o);
            }
        }
    }
    if (lane == 39) {
        taulds[2 * w]     = (sv[0] & 0xFFFFF000u) | 0xFFFu;
        taulds[2 * w + 1] = (sv[1] & 0xFFFFF000u) | 0xFFFu;
    }
    __syncthreads();

    unsigned tauU0 = taulds[g * 4 + 0], tauU1 = taulds[g * 4 + 1];
    unsigned tauU2 = taulds[g * 4 + 2], tauU3 = taulds[g * 4 + 3];
    float tauF0 = __uint_as_float(tauU0), tauF1 = __uint_as_float(tauU1);
    float tauF2 = __uint_as_float(tauU2), tauF3 = __uint_as_float(tauU3);
    int tdiag = (w == (strip >> 5)) ? (strip & 31) : 64;      // uniform per wave

    // ---- pass 2: re-stream via MFMA, float-cmp survivor test ----
    nb = bp[0];
    #pragma unroll 2
    for (int t = 0; t < 32; ++t) {
        union { uint4 u; short8 s; } bv; bv.u = nb;
        if (t < 31) nb = bp[(t + 1) * 32];
        f32x4 d = __builtin_amdgcn_mfma_f32_16x16x32_bf16(afr, bv.s, (f32x4){0.f, 0.f, 0.f, 0.f}, 0, 0, 0);
        unsigned idx = (unsigned)((cbase + t * 16) | li);
        if (t == tdiag) {                                     // uniform: diag tile
            unsigned k0 = (__float_as_uint(fmaxf(d[0], 0.f)) & 0xFFFFF000u) | idx;
            unsigned k1 = (__float_as_uint(fmaxf(d[1], 0.f)) & 0xFFFFF000u) | idx;
            unsigned k2 = (__float_as_uint(fmaxf(d[2], 0.f)) & 0xFFFFF000u) | idx;
            unsigned k3 = (__float_as_uint(fmaxf(d[3], 0.f)) & 0xFFFFF000u) | idx;
            if (selfC && es == 0) k0 = 0u;
            if (selfC && es == 1) k1 = 0u;
            if (selfC && es == 2) k2 = 0u;
            if (selfC && es == 3) k3 = 0u;
            if (k0 <= tauU0) { int s = atomicAdd(&cnt[g * 4 + 0], 1); if (s < CAP) survK[g * 4 + 0][s] = k0; }
            if (k1 <= tauU1) { int s = atomicAdd(&cnt[g * 4 + 1], 1); if (s < CAP) survK[g * 4 + 1][s] = k1; }
            if (k2 <= tauU2) { int s = atomicAdd(&cnt[g * 4 + 2], 1); if (s < CAP) survK[g * 4 + 2][s] = k2; }
            if (k3 <= tauU3) { int s = atomicAdd(&cnt[g * 4 + 3], 1); if (s < CAP) survK[g * 4 + 3][s] = k3; }
        } else {
            if (d[0] <= tauF0) {
                unsigned c = (__float_as_uint(fmaxf(d[0], 0.f)) & 0xFFFFF000u) | idx;
                int s = atomicAdd(&cnt[g * 4 + 0], 1); if (s < CAP) survK[g * 4 + 0][s] = c;
            }
            if (d[1] <= tauF1) {
                unsigned c = (__float_as_uint(fmaxf(d[1], 0.f)) & 0xFFFFF000u) | idx;
                int s = atomicAdd(&cnt[g * 4 + 1], 1); if (s < CAP) survK[g * 4 + 1][s] = c;
            }
            if (d[2] <= tauF2) {
                unsigned c = (__float_as_uint(fmaxf(d[2], 0.f)) & 0xFFFFF000u) | idx;
                int s = atomicAdd(&cnt[g * 4 + 2], 1); if (s < CAP) survK[g * 4 + 2][s] = c;
            }
            if (d[3] <= tauF3) {
                unsigned c = (__float_as_uint(fmaxf(d[3], 0.f)) & 0xFFFFF000u) | idx;
                int s = atomicAdd(&cnt[g * 4 + 3], 1); if (s < CAP) survK[g * 4 + 3][s] = c;
            }
        }
    }
    __syncthreads();

    // ---- rank survivors; ranks 1..39 -> winners (2 rows per wave) ----
    #pragma unroll
    for (int e = 0; e < 2; ++e) {
        int r = 2 * w + e;
        int S = min(cnt[r], CAP);
        if (lane < 16) survK[r][S + lane] = 0xFFFFFFFFu;      // sentinels
        for (int rr = lane; rr < S; rr += 64) {
            unsigned my = survK[r][rr];
            int c = 0;
            int S4 = (S + 3) >> 2;
            for (int s4 = 0; s4 < S4; ++s4) {
                uint4 u4 = *reinterpret_cast<const uint4*>(&survK[r][4 * s4]);
                c += (u4.x < my) + (u4.y < my) + (u4.z < my) + (u4.w < my);
            }
            if (c >= 1 && c < KSEL) winC[r][c - 1] = my;
        }
    }
    __syncthreads();

    // ---- P4: aggregate 39 winners; pack U = [x | max | mean] hi/lo ----
    const float* fb = feat + pbase * NPROP + lane;
    #pragma unroll 1
    for (int e = 0; e < 2; ++e) {
        int r = 2 * w + e;
        int qi = q0 + r;
        float mx = -3.4e38f, sm = 0.f;
        #pragma unroll 4
        for (int u = 0; u < KSEL / 4; ++u) {
            uint4 cv4 = *reinterpret_cast<const uint4*>(&winC[r][4 * u]);
            #pragma unroll
            for (int e2 = 0; e2 < 4; ++e2) {
                if (4 * u + e2 > KSEL - 2) break;             // compile-time tail skip
                unsigned comp = (e2 == 0) ? cv4.x : (e2 == 1) ? cv4.y : (e2 == 2) ? cv4.z : cv4.w;
                int j = (int)(comp & 0xFFFu);
                float dd = __uint_as_float(comp & 0xFFFFF000u);
                float wt = __expf(-10.f * dd);
                float f  = fb[(size_t)j * NPROP];
                float wf = wt * f;
                mx = fmaxf(mx, wf);
                sm += wf;
            }
        }
        float mean = sm * (1.0f / 39.0f);
        unsigned mh = b16rne(mx),   ml = b16rne(mx - fromb16(mh));
        unsigned eh = b16rne(mean), el = b16rne(mean - fromb16(eh));
        float xv = x[(pbase + qi) * FIN + lane];
        unsigned xh = b16rne(xv),   xl = b16rne(xv - fromb16(xh));
        Upk[r][lane]       = (unsigned short)xh;
        Upk[r][192 + lane] = (unsigned short)xl;
        Upk[r][64 + lane]  = (unsigned short)mh;
        Upk[r][256 + lane] = (unsigned short)ml;
        Upk[r][128 + lane] = (unsigned short)eh;
        Upk[r][320 + lane] = (unsigned short)el;
    }
    __syncthreads();

    // ---- epilogue: out[16 x 128] = U @ W_out + b_out via MFMA ----
    {
        int colc = w * 16 + li;
        const unsigned short* wp = Wpk + (size_t)colc * 576;
        f32x4 oacc = {0.f, 0.f, 0.f, 0.f};
        #pragma unroll
        for (int s = 0; s < 18; ++s) {
            int koff = (s < 6)  ? (32 * s + 8 * g)
                     : (s < 12) ? (192 + 32 * (s - 6) + 8 * g)
                                : (32 * (s - 12) + 8 * g);
            union { uint4 u; short8 s8; } av, bv;
            av.u = *reinterpret_cast<const uint4*>(&Upk[li][koff]);
            bv.u = *reinterpret_cast<const uint4*>(&wp[32 * s + 8 * g]);
            oacc = __builtin_amdgcn_mfma_f32_16x16x32_bf16(av.s8, bv.s8, oacc, 0, 0, 0);
        }
        float bb = bo[colc];
        #pragma unroll
        for (int e = 0; e < 4; ++e) {
            int orow = g * 4 + e;
            out[(size_t)(pbase + q0 + orow) * NFILT + colc] = oacc[e] + bb;
        }
    }
}

extern "C" void kernel_launch(void* const* d_in, const int* in_sizes, int n_in,
                              void* d_out, int out_size, void* d_ws, size_t ws_size,
                              hipStream_t stream)
{
    const float* x  = (const float*)d_in[0];
    const float* Wf = (const float*)d_in[1];
    const float* bf = (const float*)d_in[2];
    const float* Ws = (const float*)d_in[3];
    const float* bs = (const float*)d_in[4];
    const float* Wo = (const float*)d_in[5];
    const float* bo = (const float*)d_in[6];
    float* out = (float*)d_out;

    float*          feat = (float*)d_ws;                                       // 4 MB
    uint4*          Bpk  = (uint4*)((char*)d_ws + (size_t)ROWS * NPROP * 4);   // 512 KB
    unsigned short* Wpk  = (unsigned short*)((char*)d_ws
                             + (size_t)ROWS * NPROP * 4 + (size_t)ROWS * 32);  // 144 KB

    k0_packW<<<NFILT, 192, 0, stream>>>(Wo, Wpk);
    k1_proj <<<ROWS / 4, 256, 0, stream>>>(x, Wf, bf, Ws, bs, feat, Bpk);
    k2_knn  <<<B_ * 256, 512, 0, stream>>>(Bpk, feat, x, Wpk, bo, out);
}